// Round 7
// baseline (769.204 us; speedup 1.0000x reference)
//
#include <hip/hip_runtime.h>
#include <hip/hip_bf16.h>

typedef __attribute__((ext_vector_type(8))) __bf16 bf16x8;
typedef __attribute__((ext_vector_type(16))) float f32x16;

__device__ __forceinline__ void gload_lds16(const void* g, void* lds) {
    __builtin_amdgcn_global_load_lds(
        (const __attribute__((address_space(1))) void*)g,
        (__attribute__((address_space(3))) void*)lds, 16, 0, 0);
}

// ---------------------------------------------------------------------------
// int5 block-64 MSE quant-dequant -> bf16 (per-scale reciprocal)
// ---------------------------------------------------------------------------
__global__ __launch_bounds__(256) void quant_bf16_kernel(
    const float* __restrict__ w, __hip_bfloat16* __restrict__ wq, int nblk)
{
#pragma clang fp contract(off)
    int b = blockIdx.x * 256 + threadIdx.x;
    if (b >= nblk) return;
    const float4* src = (const float4*)(w + (size_t)b * 64);
    float v[64];
#pragma unroll
    for (int i = 0; i < 16; ++i) {
        float4 t = src[i];
        v[i*4+0] = t.x; v[i*4+1] = t.y; v[i*4+2] = t.z; v[i*4+3] = t.w;
    }
    float amax = 0.0f;
#pragma unroll
    for (int i = 0; i < 64; ++i) amax = fmaxf(amax, fabsf(v[i]));
    float base = fmaxf(amax, 1e-8f) / 15.0f;

    float best_err = __builtin_inff();
    float best_scale = base, best_rs = 0.0f;
    for (int k = 0; k < 16; ++k) {
        double sd = (k == 15) ? 1.0 : ((double)k * (0.6 / 15.0) + 0.4);
        float scale = base * (float)sd;
        float rs = 1.0f / scale;
        float err = 0.0f;
#pragma unroll
        for (int i = 0; i < 64; ++i) {
            float q = rintf(v[i] * rs);
            q = fminf(fmaxf(q, -15.0f), 15.0f);
            float d = q * scale - v[i];
            err = err + d * d;
        }
        if (err < best_err) { best_err = err; best_scale = scale; best_rs = rs; }
    }
    __hip_bfloat16* dst = wq + (size_t)b * 64;
#pragma unroll
    for (int i = 0; i < 64; ++i) {
        float q = rintf(v[i] * best_rs);
        q = fminf(fmaxf(q, -15.0f), 15.0f);
        dst[i] = __float2bfloat16(q * best_scale);
    }
}

__global__ __launch_bounds__(256) void f32_to_bf16_kernel(
    const float* __restrict__ in, __hip_bfloat16* __restrict__ out, int n8)
{
    int i = blockIdx.x * 256 + threadIdx.x;
    if (i >= n8) return;
    const float4* p = (const float4*)(in + (size_t)i * 8);
    float4 a = p[0], b = p[1];
    alignas(16) __hip_bfloat16 r[8];
    r[0] = __float2bfloat16(a.x); r[1] = __float2bfloat16(a.y);
    r[2] = __float2bfloat16(a.z); r[3] = __float2bfloat16(a.w);
    r[4] = __float2bfloat16(b.x); r[5] = __float2bfloat16(b.y);
    r[6] = __float2bfloat16(b.z); r[7] = __float2bfloat16(b.w);
    *(uint4*)(out + (size_t)i * 8) = *(const uint4*)r;
}

// ---------------------------------------------------------------------------
// 256x256 tile, BK=64, 8 waves (2Mx4N), per-wave 128x64, MFMA 32x32x16.
// LDS layout per buffer (64KB, dbuf at +64KB):
//   A: grp g=row/32 (0..7): g*4096 + oct*512 + (row%32)*16   (oct = k/8, 0..7)
//   B: +32768, same with col.
// Fragment read (m,s): 1 KB fully contiguous per wave -> conflict-free:
//   addr = buf + (wr*4+m)*4096 + s*1024 + (lane>>5)*512 + (lane&31)*16
// Staging: linear gload_lds dest (region i = 8192B, grps 2i,2i+1); global
// source permuted accordingly: thread t -> row (t>>8)*32+(t&31), oct (t>>5)&7.
// Schedule per K-tile (r6 skeleton: 1 barrier/tile, stage-at-start):
//   RD(s0); STAGE t+1 x8; RD(s1); [lgkm6 MFMA8(s0)]; RD(s2); [lgkm6 MFMA8(s1)];
//   RD(s3); [lgkm6 MFMA8(s2)]; [lgkm0 MFMA8(s3)]; vmcnt(0); barrier.
// MFMA8 = 8 independent accs (4m x 2n) per k-step; acc chains depth 4 over s.
// Ledger: RAW -- buf[cur] staged in tile t-1, all waves vmcnt(0) before the
// barrier ending t-1; first read of buf[cur] is after that barrier. WAR --
// stagings into buf[nxt] overwrite data whose readers (tile t-1) finished
// their lgkm-drained reads before that same barrier.
// ---------------------------------------------------------------------------
#define RDA(dst, bufOff, s) { \
    dst[0] = *(const bf16x8*)(smem + (bufOff) + aBase + 0u*4096u + (s)*1024u); \
    dst[1] = *(const bf16x8*)(smem + (bufOff) + aBase + 1u*4096u + (s)*1024u); \
    dst[2] = *(const bf16x8*)(smem + (bufOff) + aBase + 2u*4096u + (s)*1024u); \
    dst[3] = *(const bf16x8*)(smem + (bufOff) + aBase + 3u*4096u + (s)*1024u); }

#define RDB(dst, bufOff, s) { \
    dst[0] = *(const bf16x8*)(smem + (bufOff) + bBase + 0u*4096u + (s)*1024u); \
    dst[1] = *(const bf16x8*)(smem + (bufOff) + bBase + 1u*4096u + (s)*1024u); }

#define MFMA8(aS, bS) { \
    acc[0][0] = __builtin_amdgcn_mfma_f32_32x32x16_bf16(aS[0], bS[0], acc[0][0],0,0,0); \
    acc[0][1] = __builtin_amdgcn_mfma_f32_32x32x16_bf16(aS[0], bS[1], acc[0][1],0,0,0); \
    acc[1][0] = __builtin_amdgcn_mfma_f32_32x32x16_bf16(aS[1], bS[0], acc[1][0],0,0,0); \
    acc[1][1] = __builtin_amdgcn_mfma_f32_32x32x16_bf16(aS[1], bS[1], acc[1][1],0,0,0); \
    acc[2][0] = __builtin_amdgcn_mfma_f32_32x32x16_bf16(aS[2], bS[0], acc[2][0],0,0,0); \
    acc[2][1] = __builtin_amdgcn_mfma_f32_32x32x16_bf16(aS[2], bS[1], acc[2][1],0,0,0); \
    acc[3][0] = __builtin_amdgcn_mfma_f32_32x32x16_bf16(aS[3], bS[0], acc[3][0],0,0,0); \
    acc[3][1] = __builtin_amdgcn_mfma_f32_32x32x16_bf16(aS[3], bS[1], acc[3][1],0,0,0); }

#define STAGE_ALL(dstOff, kElem) { \
    gload_lds16(uA + (size_t)(voff + (kElem) + 0u*K64i), smem + (dstOff) + 0u*8192u + wOff); \
    gload_lds16(uA + (size_t)(voff + (kElem) + 1u*K64i), smem + (dstOff) + 1u*8192u + wOff); \
    gload_lds16(uA + (size_t)(voff + (kElem) + 2u*K64i), smem + (dstOff) + 2u*8192u + wOff); \
    gload_lds16(uA + (size_t)(voff + (kElem) + 3u*K64i), smem + (dstOff) + 3u*8192u + wOff); \
    gload_lds16(uB + (size_t)(voff + (kElem) + 0u*K64i), smem + (dstOff) + 32768u + 0u*8192u + wOff); \
    gload_lds16(uB + (size_t)(voff + (kElem) + 1u*K64i), smem + (dstOff) + 32768u + 1u*8192u + wOff); \
    gload_lds16(uB + (size_t)(voff + (kElem) + 2u*K64i), smem + (dstOff) + 32768u + 2u*8192u + wOff); \
    gload_lds16(uB + (size_t)(voff + (kElem) + 3u*K64i), smem + (dstOff) + 32768u + 3u*8192u + wOff); }

#define LGKM6() { asm volatile("s_waitcnt lgkmcnt(6)" ::: "memory"); \
    __builtin_amdgcn_sched_barrier(0); }
#define LGKM0() { asm volatile("s_waitcnt lgkmcnt(0)" ::: "memory"); \
    __builtin_amdgcn_sched_barrier(0); }
#define BARRIER() { __builtin_amdgcn_sched_barrier(0); \
    __builtin_amdgcn_s_barrier(); __builtin_amdgcn_sched_barrier(0); }

template <int EPI>  // 0: C=bf16(relu(acc)^2), 1: C=f32 acc
__global__ __launch_bounds__(512, 1) void gemm256_kernel(
    const __hip_bfloat16* __restrict__ A,   // M x K
    const __hip_bfloat16* __restrict__ B,   // N x K
    void* __restrict__ Cout, int M, int N, int K)
{
    extern __shared__ char smem[];

    const int t    = threadIdx.x;
    const int lane = t & 63;
    const int w    = t >> 6;
    const int wr   = w >> 2;        // 0..1 (128-row half)
    const int wc   = w & 3;         // 0..3 (64-col quarter)
    const int l5   = lane & 31;
    const int h2   = lane >> 5;
    const uint wOff = (uint)w * 1024u;

    // XCD-aware swizzle (grids are multiples of 8)
    const int cpx = gridDim.x >> 3;
    int bid = blockIdx.x;
    bid = (bid & 7) * cpx + (bid >> 3);
    const int nN = N >> 8;
    const int bm = bid / nN;
    const int bn = bid % nN;
    const int rowBase = bm << 8;
    const int colBase = bn << 8;

    const __hip_bfloat16* uA = A + (size_t)rowBase * (size_t)K;
    const __hip_bfloat16* uB = B + (size_t)colBase * (size_t)K;

    // staging source offset (thread-invariant part):
    // row-in-64 = (t>>8)*32 + (t&31), k-octet = (t>>5)&7
    const uint rS   = ((uint)(t >> 8)) * 32u + (uint)(t & 31);
    const uint octS = ((uint)(t >> 5)) & 7u;
    const uint voff = rS * (uint)K + octS * 8u;
    const uint K64i = (uint)K * 64u;            // 64-row stride in elements

    // fragment read bases (conflict-free contiguous)
    const uint aBase = (uint)(wr * 4) * 4096u + (uint)h2 * 512u + (uint)l5 * 16u;
    const uint bBase = 32768u + (uint)(wc * 2) * 4096u + (uint)h2 * 512u + (uint)l5 * 16u;

    f32x16 acc[4][2] = {};
    bf16x8 a0[4], a1[4], b0[2], b1[2];

    // ---- prologue: tile0 -> buf0 ----
    STAGE_ALL(0u, 0u);
    asm volatile("s_waitcnt vmcnt(0)" ::: "memory");
    BARRIER();

    const int NT = K >> 6;
    for (int tt = 0; tt < NT; ++tt) {
        const uint bufOff = (uint)(tt & 1) * 65536u;
        const uint nxtOff = bufOff ^ 65536u;
        const bool pf = (tt + 1 < NT);
        const uint kN = ((uint)(tt + 1)) << 6;

        RDA(a0, bufOff, 0u); RDB(b0, bufOff, 0u);
        if (pf) STAGE_ALL(nxtOff, kN);
        RDA(a1, bufOff, 1u); RDB(b1, bufOff, 1u);

        LGKM6();                       // a0/b0 landed (a1/b1 may be in flight)
        __builtin_amdgcn_s_setprio(1); MFMA8(a0, b0); __builtin_amdgcn_s_setprio(0);
        RDA(a0, bufOff, 2u); RDB(b0, bufOff, 2u);

        LGKM6();                       // a1/b1 landed
        __builtin_amdgcn_s_setprio(1); MFMA8(a1, b1); __builtin_amdgcn_s_setprio(0);
        RDA(a1, bufOff, 3u); RDB(b1, bufOff, 3u);

        LGKM6();                       // s2 frags landed
        __builtin_amdgcn_s_setprio(1); MFMA8(a0, b0); __builtin_amdgcn_s_setprio(0);

        LGKM0();                       // s3 frags landed
        __builtin_amdgcn_s_setprio(1); MFMA8(a1, b1); __builtin_amdgcn_s_setprio(0);

        if (pf) asm volatile("s_waitcnt vmcnt(0)" ::: "memory");
        BARRIER();
    }

    // ---- epilogue: 32x32 C/D layout col=lane&31, row=(r&3)+8*(r>>2)+4*h2 ----
    if (EPI == 0) {
        __hip_bfloat16* Cb = (__hip_bfloat16*)Cout;
#pragma unroll
        for (int m = 0; m < 4; ++m)
#pragma unroll
            for (int n = 0; n < 2; ++n)
#pragma unroll
                for (int r = 0; r < 16; ++r) {
                    size_t row = rowBase + wr*128 + m*32 + (r & 3) + 8*(r >> 2) + 4*h2;
                    size_t col = colBase + wc*64 + n*32 + l5;
                    float v = fmaxf(acc[m][n][r], 0.0f);
                    Cb[row * N + col] = __float2bfloat16(v * v);
                }
    } else {
        float* Cf = (float*)Cout;
#pragma unroll
        for (int m = 0; m < 4; ++m)
#pragma unroll
            for (int n = 0; n < 2; ++n)
#pragma unroll
                for (int r = 0; r < 16; ++r) {
                    size_t row = rowBase + wr*128 + m*32 + (r & 3) + 8*(r >> 2) + 4*h2;
                    size_t col = colBase + wc*64 + n*32 + l5;
                    Cf[row * N + col] = acc[m][n][r];
                }
    }
}

// ---------------------------------------------------------------------------
extern "C" void kernel_launch(void* const* d_in, const int* in_sizes, int n_in,
                              void* d_out, int out_size, void* d_ws, size_t ws_size,
                              hipStream_t stream) {
    const float* x      = (const float*)d_in[0];  // 8192 x 2048
    const float* w_fc   = (const float*)d_in[1];  // 8192 x 2048
    const float* w_proj = (const float*)d_in[2];  // 2048 x 8192
    float* out = (float*)d_out;                   // 8192 x 2048

    const int DIM = 2048, HID = 8192, M = 8192;

    char* ws = (char*)d_ws;
    __hip_bfloat16* Xb  = (__hip_bfloat16*)ws;
    __hip_bfloat16* Wfc = (__hip_bfloat16*)(ws + (size_t)M * DIM * 2);
    __hip_bfloat16* Wpj = (__hip_bfloat16*)(ws + (size_t)(M * DIM + (size_t)HID * DIM) * 2);
    __hip_bfloat16* H2  = (__hip_bfloat16*)(ws + (size_t)(M * DIM + 2 * (size_t)HID * DIM) * 2);

    (void)hipFuncSetAttribute((const void*)gemm256_kernel<0>,
                              hipFuncAttributeMaxDynamicSharedMemorySize, 131072);
    (void)hipFuncSetAttribute((const void*)gemm256_kernel<1>,
                              hipFuncAttributeMaxDynamicSharedMemorySize, 131072);

    int nblk = HID * DIM / 64;
    quant_bf16_kernel<<<nblk / 256, 256, 0, stream>>>(w_fc, Wfc, nblk);
    quant_bf16_kernel<<<nblk / 256, 256, 0, stream>>>(w_proj, Wpj, nblk);

    int n8 = M * DIM / 8;
    f32_to_bf16_kernel<<<n8 / 256, 256, 0, stream>>>(x, Xb, n8);

    // H2 = bf16( relu(X @ Wfc^T)^2 )  [8192 x 8192]
    gemm256_kernel<0><<<(M/256)*(HID/256), 512, 131072, stream>>>(
        Xb, Wfc, (void*)H2, M, HID, DIM);

    // out = H2 @ Wpj^T  [8192 x 2048] f32
    gemm256_kernel<1><<<(M/256)*(DIM/256), 512, 131072, stream>>>(
        H2, Wpj, (void*)out, M, DIM, HID);
}

// Round 8
// 610.663 us; speedup vs baseline: 1.2596x; 1.2596x over previous
//
#include <hip/hip_runtime.h>
#include <hip/hip_bf16.h>

typedef __attribute__((ext_vector_type(8))) __bf16 bf16x8;
typedef __attribute__((ext_vector_type(4))) float f32x4;

__device__ __forceinline__ void gload_lds16(const void* g, void* lds) {
    __builtin_amdgcn_global_load_lds(
        (const __attribute__((address_space(1))) void*)g,
        (__attribute__((address_space(3))) void*)lds, 16, 0, 0);
}

// ---------------------------------------------------------------------------
// int5 block-64 MSE quant-dequant -> bf16 (per-scale reciprocal)
// ---------------------------------------------------------------------------
__global__ __launch_bounds__(256) void quant_bf16_kernel(
    const float* __restrict__ w, __hip_bfloat16* __restrict__ wq, int nblk)
{
#pragma clang fp contract(off)
    int b = blockIdx.x * 256 + threadIdx.x;
    if (b >= nblk) return;
    const float4* src = (const float4*)(w + (size_t)b * 64);
    float v[64];
#pragma unroll
    for (int i = 0; i < 16; ++i) {
        float4 t = src[i];
        v[i*4+0] = t.x; v[i*4+1] = t.y; v[i*4+2] = t.z; v[i*4+3] = t.w;
    }
    float amax = 0.0f;
#pragma unroll
    for (int i = 0; i < 64; ++i) amax = fmaxf(amax, fabsf(v[i]));
    float base = fmaxf(amax, 1e-8f) / 15.0f;

    float best_err = __builtin_inff();
    float best_scale = base, best_rs = 0.0f;
    for (int k = 0; k < 16; ++k) {
        double sd = (k == 15) ? 1.0 : ((double)k * (0.6 / 15.0) + 0.4);
        float scale = base * (float)sd;
        float rs = 1.0f / scale;
        float err = 0.0f;
#pragma unroll
        for (int i = 0; i < 64; ++i) {
            float q = rintf(v[i] * rs);
            q = fminf(fmaxf(q, -15.0f), 15.0f);
            float d = q * scale - v[i];
            err = err + d * d;
        }
        if (err < best_err) { best_err = err; best_scale = scale; best_rs = rs; }
    }
    __hip_bfloat16* dst = wq + (size_t)b * 64;
#pragma unroll
    for (int i = 0; i < 64; ++i) {
        float q = rintf(v[i] * best_rs);
        q = fminf(fmaxf(q, -15.0f), 15.0f);
        dst[i] = __float2bfloat16(q * best_scale);
    }
}

__global__ __launch_bounds__(256) void f32_to_bf16_kernel(
    const float* __restrict__ in, __hip_bfloat16* __restrict__ out, int n8)
{
    int i = blockIdx.x * 256 + threadIdx.x;
    if (i >= n8) return;
    const float4* p = (const float4*)(in + (size_t)i * 8);
    float4 a = p[0], b = p[1];
    alignas(16) __hip_bfloat16 r[8];
    r[0] = __float2bfloat16(a.x); r[1] = __float2bfloat16(a.y);
    r[2] = __float2bfloat16(a.z); r[3] = __float2bfloat16(a.w);
    r[4] = __float2bfloat16(b.x); r[5] = __float2bfloat16(b.y);
    r[6] = __float2bfloat16(b.z); r[7] = __float2bfloat16(b.w);
    *(uint4*)(out + (size_t)i * 8) = *(const uint4*)r;
}

// ---------------------------------------------------------------------------
// 256x256 tile, BK=64, 8 waves (2Mx4N), 16x16x32 MFMA, row-major swizzled
// LDS (phys = logical ^ ((row&7)<<4)), linear wave-contiguous staging.
// One barrier per K-tile. REGISTER-PIPELINED frag reads with COUNTED lgkm:
//   issue: [STAGE t+1 x8(vm)] [LDB8 + aC(s0,s1)] sb0 [aD(s2,s3)]
//   lgkm(4)  -> B,s0,s1 landed (s2,s3 in flight)   MFMA w0 (acc0,1)
//   issue aC(s4,s5); lgkm(4) -> s2,s3 landed        MFMA w1 (acc2,3)
//   issue aD(s6,s7); lgkm(4) -> s4,s5 landed        MFMA w2 (acc4,5)
//   lgkm(0)                                         MFMA w3 (acc6,7)
//   vmcnt(0); barrier
// The 4 in-flight ds_reads drain under each 16-MFMA burst -> LDS pipe
// overlaps MFMA pipe instead of alternating with it.
// Ledger: RAW -- buf[cur] staged during t-1, every wave vmcnt(0) before the
// barrier ending t-1. WAR -- stagings into buf[nxt] overwrite data whose
// readers finished (lgkm-drained) before that same barrier. asm "memory"
// clobbers order all memory ops across the waitcnts; sched_barrier(0) after
// each waitcnt keeps MFMAs from hoisting above them (rule 18).
// ---------------------------------------------------------------------------
#define LDA2(d, base, s) { \
    d[0] = *(const bf16x8*)(smem + (base) + aB + (s)*2048u + cb0); \
    d[1] = *(const bf16x8*)(smem + (base) + aB + (s)*2048u + cb1); }

#define LDB8(base) { \
    bf[0][0] = *(const bf16x8*)(smem + (base) + bB + 0u    + cb0); \
    bf[0][1] = *(const bf16x8*)(smem + (base) + bB + 0u    + cb1); \
    bf[1][0] = *(const bf16x8*)(smem + (base) + bB + 2048u + cb0); \
    bf[1][1] = *(const bf16x8*)(smem + (base) + bB + 2048u + cb1); \
    bf[2][0] = *(const bf16x8*)(smem + (base) + bB + 4096u + cb0); \
    bf[2][1] = *(const bf16x8*)(smem + (base) + bB + 4096u + cb1); \
    bf[3][0] = *(const bf16x8*)(smem + (base) + bB + 6144u + cb0); \
    bf[3][1] = *(const bf16x8*)(smem + (base) + bB + 6144u + cb1); }

#define MF8(q, a2) { \
    acc[q][0] = __builtin_amdgcn_mfma_f32_16x16x32_bf16(a2[0], bf[0][0], acc[q][0],0,0,0); \
    acc[q][0] = __builtin_amdgcn_mfma_f32_16x16x32_bf16(a2[1], bf[0][1], acc[q][0],0,0,0); \
    acc[q][1] = __builtin_amdgcn_mfma_f32_16x16x32_bf16(a2[0], bf[1][0], acc[q][1],0,0,0); \
    acc[q][1] = __builtin_amdgcn_mfma_f32_16x16x32_bf16(a2[1], bf[1][1], acc[q][1],0,0,0); \
    acc[q][2] = __builtin_amdgcn_mfma_f32_16x16x32_bf16(a2[0], bf[2][0], acc[q][2],0,0,0); \
    acc[q][2] = __builtin_amdgcn_mfma_f32_16x16x32_bf16(a2[1], bf[2][1], acc[q][2],0,0,0); \
    acc[q][3] = __builtin_amdgcn_mfma_f32_16x16x32_bf16(a2[0], bf[3][0], acc[q][3],0,0,0); \
    acc[q][3] = __builtin_amdgcn_mfma_f32_16x16x32_bf16(a2[1], bf[3][1], acc[q][3],0,0,0); }

#define STAGE(base, eoff, ldsOff) \
    gload_lds16((base) + (size_t)((eoff) + voff), smem + (ldsOff) + wOff)

#define SB0() __builtin_amdgcn_sched_barrier(0)
#define LGKM(n) { asm volatile("s_waitcnt lgkmcnt(" #n ")" ::: "memory"); SB0(); }
#define BARRIER() { SB0(); __builtin_amdgcn_s_barrier(); SB0(); }

template <int EPI>  // 0: C=bf16(relu(acc)^2), 1: C=f32 acc
__global__ __launch_bounds__(512, 1) void gemm256_kernel(
    const __hip_bfloat16* __restrict__ A,   // M x K
    const __hip_bfloat16* __restrict__ B,   // N x K
    void* __restrict__ Cout, int M, int N, int K)
{
    extern __shared__ char smem[];

    const int t    = threadIdx.x;
    const int lane = t & 63;
    const int w    = t >> 6;
    const int wr   = w >> 2;
    const int wc   = w & 3;
    const int lo   = lane & 15;
    const int hi   = lane >> 4;
    const uint wOff = (uint)w * 1024u;

    const int cpx = gridDim.x >> 3;
    int bid = blockIdx.x;
    bid = (bid & 7) * cpx + (bid >> 3);
    const int nN = N >> 8;
    const int bm = bid / nN;
    const int bn = bid % nN;
    const int rowBase = bm << 8;
    const int colBase = bn << 8;

    // uniform bases + per-thread staging offset (inverse-swizzled, linear LDS)
    const __hip_bfloat16* uA = A + (size_t)rowBase * (size_t)K;
    const __hip_bfloat16* uB = B + (size_t)colBase * (size_t)K;
    uint o0 = (uint)t * 16u;
    uint p0 = o0 ^ (((o0 >> 7) & 7u) << 4);
    const uint voff = (p0 >> 7) * (uint)K + ((p0 & 127u) >> 1);
    const uint K64 = (uint)K * 64u;

    // LDS read addressing (swizzled)
    const uint sw  = (uint)(lo & 7) << 4;
    const uint aB  = (uint)wr * 16384u + (uint)lo * 128u;
    const uint bB  = 32768u + (uint)(wc >> 1) * 16384u
                   + ((uint)(wc & 1) * 64u + (uint)lo) * 128u;
    const uint cb0 = ((uint)hi * 16u) ^ sw;
    const uint cb1 = (64u + (uint)hi * 16u) ^ sw;

    f32x4 acc[8][4] = {};
    bf16x8 aC0[2], aC1[2], aD0[2], aD1[2], bf[4][2];

    // ---- prologue: tile0 -> buf0 ----
    STAGE(uA, 0u,     0u);      STAGE(uA, K64,    8192u);
    STAGE(uA, 2u*K64, 16384u);  STAGE(uA, 3u*K64, 24576u);
    STAGE(uB, 0u,     32768u);  STAGE(uB, K64,    40960u);
    STAGE(uB, 2u*K64, 49152u);  STAGE(uB, 3u*K64, 57344u);
    asm volatile("s_waitcnt vmcnt(0)" ::: "memory");
    BARRIER();

    const int NT = K >> 6;
    for (int tt = 0; tt < NT; ++tt) {
        const uint bufOff = (uint)(tt & 1) * 65536u;
        const uint nxtOff = bufOff ^ 65536u;
        const bool pf = (tt + 1 < NT);
        const uint kN = ((uint)(tt + 1)) << 6;

        if (pf) {
            STAGE(uA, kN,          nxtOff + 0u);
            STAGE(uA, kN + K64,    nxtOff + 8192u);
            STAGE(uA, kN + 2u*K64, nxtOff + 16384u);
            STAGE(uA, kN + 3u*K64, nxtOff + 24576u);
            STAGE(uB, kN,          nxtOff + 32768u);
            STAGE(uB, kN + K64,    nxtOff + 40960u);
            STAGE(uB, kN + 2u*K64, nxtOff + 49152u);
            STAGE(uB, kN + 3u*K64, nxtOff + 57344u);
        }
        SB0();   // pin stagings at tile start

        // issue: B(8) + w0 frags(4), then w1 frags(4) (order fenced)
        LDB8(bufOff);
        LDA2(aC0, bufOff, 0u); LDA2(aC1, bufOff, 1u);
        SB0();
        LDA2(aD0, bufOff, 2u); LDA2(aD1, bufOff, 3u);

        LGKM(4);   // B + s0,s1 landed; s2,s3 still in flight
        __builtin_amdgcn_s_setprio(1); MF8(0, aC0); MF8(1, aC1); __builtin_amdgcn_s_setprio(0);
        LDA2(aC0, bufOff, 4u); LDA2(aC1, bufOff, 5u);

        LGKM(4);   // s2,s3 landed; s4,s5 in flight
        __builtin_amdgcn_s_setprio(1); MF8(2, aD0); MF8(3, aD1); __builtin_amdgcn_s_setprio(0);
        LDA2(aD0, bufOff, 6u); LDA2(aD1, bufOff, 7u);

        LGKM(4);   // s4,s5 landed; s6,s7 in flight
        __builtin_amdgcn_s_setprio(1); MF8(4, aC0); MF8(5, aC1); __builtin_amdgcn_s_setprio(0);

        LGKM(0);   // s6,s7 landed
        __builtin_amdgcn_s_setprio(1); MF8(6, aD0); MF8(7, aD1); __builtin_amdgcn_s_setprio(0);

        if (pf) asm volatile("s_waitcnt vmcnt(0)" ::: "memory");
        BARRIER();
    }

    // ---- epilogue: C/D layout col=lane&15, row=(lane>>4)*4+r ----
    if (EPI == 0) {
        __hip_bfloat16* Cb = (__hip_bfloat16*)Cout;
#pragma unroll
        for (int i = 0; i < 8; ++i)
#pragma unroll
            for (int j = 0; j < 4; ++j)
#pragma unroll
                for (int r = 0; r < 4; ++r) {
                    size_t row = rowBase + wr*128 + i*16 + hi*4 + r;
                    size_t col = colBase + wc*64 + j*16 + lo;
                    float v = fmaxf(acc[i][j][r], 0.0f);
                    Cb[row * N + col] = __float2bfloat16(v * v);
                }
    } else {
        float* Cf = (float*)Cout;
#pragma unroll
        for (int i = 0; i < 8; ++i)
#pragma unroll
            for (int j = 0; j < 4; ++j)
#pragma unroll
                for (int r = 0; r < 4; ++r) {
                    size_t row = rowBase + wr*128 + i*16 + hi*4 + r;
                    size_t col = colBase + wc*64 + j*16 + lo;
                    Cf[row * N + col] = acc[i][j][r];
                }
    }
}

// ---------------------------------------------------------------------------
extern "C" void kernel_launch(void* const* d_in, const int* in_sizes, int n_in,
                              void* d_out, int out_size, void* d_ws, size_t ws_size,
                              hipStream_t stream) {
    const float* x      = (const float*)d_in[0];  // 8192 x 2048
    const float* w_fc   = (const float*)d_in[1];  // 8192 x 2048
    const float* w_proj = (const float*)d_in[2];  // 2048 x 8192
    float* out = (float*)d_out;                   // 8192 x 2048

    const int DIM = 2048, HID = 8192, M = 8192;

    char* ws = (char*)d_ws;
    __hip_bfloat16* Xb  = (__hip_bfloat16*)ws;
    __hip_bfloat16* Wfc = (__hip_bfloat16*)(ws + (size_t)M * DIM * 2);
    __hip_bfloat16* Wpj = (__hip_bfloat16*)(ws + (size_t)(M * DIM + (size_t)HID * DIM) * 2);
    __hip_bfloat16* H2  = (__hip_bfloat16*)(ws + (size_t)(M * DIM + 2 * (size_t)HID * DIM) * 2);

    (void)hipFuncSetAttribute((const void*)gemm256_kernel<0>,
                              hipFuncAttributeMaxDynamicSharedMemorySize, 131072);
    (void)hipFuncSetAttribute((const void*)gemm256_kernel<1>,
                              hipFuncAttributeMaxDynamicSharedMemorySize, 131072);

    int nblk = HID * DIM / 64;
    quant_bf16_kernel<<<nblk / 256, 256, 0, stream>>>(w_fc, Wfc, nblk);
    quant_bf16_kernel<<<nblk / 256, 256, 0, stream>>>(w_proj, Wpj, nblk);

    int n8 = M * DIM / 8;
    f32_to_bf16_kernel<<<n8 / 256, 256, 0, stream>>>(x, Xb, n8);

    // H2 = bf16( relu(X @ Wfc^T)^2 )  [8192 x 8192]
    gemm256_kernel<0><<<(M/256)*(HID/256), 512, 131072, stream>>>(
        Xb, Wfc, (void*)H2, M, HID, DIM);

    // out = H2 @ Wpj^T  [8192 x 2048] f32
    gemm256_kernel<1><<<(M/256)*(DIM/256), 512, 131072, stream>>>(
        H2, Wpj, (void*)out, M, DIM, HID);
}